// Round 11
// baseline (576.720 us; speedup 1.0000x reference)
//
#include <hip/hip_runtime.h>

typedef unsigned short u16;
typedef unsigned int   u32;

#define BT   4096
#define TSEQ 64
#define NB   64

typedef __attribute__((ext_vector_type(8))) short  short8;
typedef __attribute__((ext_vector_type(4))) float  f32x4;
typedef __attribute__((ext_vector_type(2))) _Float16 h2;

__device__ __forceinline__ float bf(u16 v) {
    u32 u = ((u32)v) << 16;
    return __builtin_bit_cast(float, u);
}
__device__ __forceinline__ u16 f2b(float f) {
    u32 u = __builtin_bit_cast(u32, f);
    return (u16)((u + 0x7fffu + ((u >> 16) & 1u)) >> 16);  // RNE
}
__device__ __forceinline__ float lrelu(float x) { return x > 0.f ? x : 0.2f * x; }
__device__ __forceinline__ h2 i2h(int v) { return __builtin_bit_cast(h2, v); }
__device__ __forceinline__ float dot2(int hbits, int wbits, float acc) {
#if __has_builtin(__builtin_amdgcn_fdot2)
    return __builtin_amdgcn_fdot2(i2h(hbits), i2h(wbits), acc, false);
#else
    h2 a = i2h(hbits), b = i2h(wbits);
    return acc + (float)a.x * (float)b.x + (float)a.y * (float)b.y;
#endif
}
__device__ __forceinline__ float fsigm(float x) { return 1.f / (1.f + __expf(-x)); }
__device__ __forceinline__ float ftanh(float x) { return 1.f - 2.f / (__expf(2.f * x) + 1.f); }
__device__ __forceinline__ float ldf(const void* p, int i, int f32) {
    return f32 ? ((const float*)p)[i] : bf(((const u16*)p)[i]);
}
__device__ __forceinline__ u16 ldb(const void* p, int i, int f32) {
    return f32 ? f2b(((const float*)p)[i]) : ((const u16*)p)[i];
}

struct PrepPtrs {
    const void *x, *W1, *b1, *W2, *b2, *W3, *b3, *W4, *b4;
    const void *Wr, *Wk, *Wpim, *Wpir, *Wv;
    const u16* probe;
    u16 *featbf, *PF, *PBk, *PBpim, *PBpir;
    float* scal; int* flag;
};

#define PACK_BLKS 6208
#define CONV_BLKS 2048   // 2 images per block

// ================= K1: prep = sniff(inline) + pack + conv ===================
__global__ __launch_bounds__(256) void prep_kernel(PrepPtrs P)
{
    const int bid = blockIdx.x, tid = threadIdx.x;
    const int lane = tid & 63;
    u16 pv = P.probe[2 * lane];
    int e = (pv >> 7) & 0xFF;
    unsigned long long m = __ballot(pv == 0 || (e >= 100 && e <= 130));
    const int f32 = (__popcll(m) < 48) ? 1 : 0;

    if (bid == 0 && tid < 32) { P.scal[tid] = 0.f; if (tid == 0) *P.flag = f32; }

    if (bid < PACK_BLKS) {
        const int blk = bid;
        if (blk < 1024) {
            int gid = blk * 256 + tid;
            int k = gid >> 10, col = gid & 1023;
            float f = ldf(P.Wr, gid, f32);
            _Float16 h = (_Float16)f;
            P.PF[((size_t)(k >> 3) * 1024 + col) * 8 + (k & 7)] =
                __builtin_bit_cast(unsigned short, h);
        } else if (blk < 2048) {
            int gid = (blk - 1024) * 256 + tid;
            int k = gid >> 10, col = gid & 1023;
            P.PBk[((((size_t)(k >> 5) << 10) + col) * 4 + ((k >> 3) & 3)) * 8 + (k & 7)] =
                ldb(P.Wk, gid, f32);
        } else if (blk < 6144) {
            int gid = (blk - 2048) * 256 + tid;
            int k = gid >> 12, col = gid & 4095;
            P.PBpim[((((size_t)(k >> 5) << 12) + col) * 4 + ((k >> 3) & 3)) * 8 + (k & 7)] =
                ldb(P.Wpim, gid, f32);
        } else {
            int gid = (blk - 6144) * 256 + tid;   // 16384: 256 k x 64 cols
            int k = gid >> 6, col = gid & 63;
            u16 v = 0;
            if (col < 36)      v = ldb(P.Wpir, k * 36 + col, f32);
            else if (col == 36) v = ldb(P.Wv, k, f32);
            P.PBpir[(((size_t)(k >> 5) * 64 + col) * 4 + ((k >> 3) & 3)) * 8 + (k & 7)] = v;
        }
        return;
    }

    // ---- conv branch: 2 images per block; LDS-staged bf16 weights ----
    __shared__ __align__(16) u16 wl[19184];
    __shared__ float xs[2][832];
    __shared__ float c1[2][384];
    __shared__ float c2[2][480];
    __shared__ float c3[2][128];
    const int pair = bid - PACK_BLKS;
    const int sub = tid >> 7, stid = tid & 127;
    const int bt = pair * 2 + sub;

    {
        const void* sp[8] = {P.W1, P.b1, P.W2, P.b2, P.W3, P.b3, P.W4, P.b4};
        const int   sn[8] = {512, 16, 2048, 32, 8192, 64, 8192, 128};
        int o = 0;
        for (int s = 0; s < 8; s++) {
            for (int i = tid; i < sn[s]; i += 256) wl[o + i] = ldb(sp[s], i, f32);
            o += sn[s];
        }
    }
    for (int i = stid; i < 832; i += 128) xs[sub][i] = ldf(P.x, bt * 832 + i, f32);
    __syncthreads();

    for (int idx = stid; idx < 96; idx += 128) {
        int pos = idx >> 2, g = idx & 3;
        int oh = pos >> 2, ow = pos & 3;
        float a0 = bf(wl[512 + g * 4]), a1 = bf(wl[513 + g * 4]),
              a2 = bf(wl[514 + g * 4]), a3 = bf(wl[515 + g * 4]);
        for (int kh = 0; kh < 2; kh++)
            for (int kw = 0; kw < 2; kw++)
#pragma unroll
                for (int ic = 0; ic < 8; ic++) {
                    float xv = xs[sub][(2 * oh + kh) * 64 + (2 * ow + kw) * 8 + ic];
                    ushort4 w = *(const ushort4*)&wl[((kh * 2 + kw) * 8 + ic) * 16 + g * 4];
                    a0 += xv * bf(w.x); a1 += xv * bf(w.y);
                    a2 += xv * bf(w.z); a3 += xv * bf(w.w);
                }
        c1[sub][pos * 16 + g * 4]     = lrelu(a0);
        c1[sub][pos * 16 + g * 4 + 1] = lrelu(a1);
        c1[sub][pos * 16 + g * 4 + 2] = lrelu(a2);
        c1[sub][pos * 16 + g * 4 + 3] = lrelu(a3);
    }
    __syncthreads();

    for (int idx = stid; idx < 120; idx += 128) {
        int pos = idx >> 3, g = idx & 7;
        int oh = pos / 3, ow = pos % 3;
        float a0 = bf(wl[2576 + g * 4]), a1 = bf(wl[2577 + g * 4]),
              a2 = bf(wl[2578 + g * 4]), a3 = bf(wl[2579 + g * 4]);
        for (int kh = 0; kh < 2; kh++)
            for (int kw = 0; kw < 2; kw++)
#pragma unroll
                for (int ic = 0; ic < 16; ic++) {
                    float xv = c1[sub][((oh + kh) * 4 + (ow + kw)) * 16 + ic];
                    ushort4 w = *(const ushort4*)&wl[528 + ((kh * 2 + kw) * 16 + ic) * 32 + g * 4];
                    a0 += xv * bf(w.x); a1 += xv * bf(w.y);
                    a2 += xv * bf(w.z); a3 += xv * bf(w.w);
                }
        c2[sub][pos * 32 + g * 4]     = lrelu(a0);
        c2[sub][pos * 32 + g * 4 + 1] = lrelu(a1);
        c2[sub][pos * 32 + g * 4 + 2] = lrelu(a2);
        c2[sub][pos * 32 + g * 4 + 3] = lrelu(a3);
    }
    __syncthreads();

    for (int idx = stid; idx < 32; idx += 128) {
        int oh = idx >> 4, g = idx & 15;
        float a0 = bf(wl[10800 + g * 4]), a1 = bf(wl[10801 + g * 4]),
              a2 = bf(wl[10802 + g * 4]), a3 = bf(wl[10803 + g * 4]);
        for (int kh = 0; kh < 2; kh++)
            for (int kw = 0; kw < 2; kw++)
#pragma unroll
                for (int ic = 0; ic < 32; ic++) {
                    float xv = c2[sub][((2 * oh + kh) * 3 + kw) * 32 + ic];
                    ushort4 w = *(const ushort4*)&wl[2608 + ((kh * 2 + kw) * 32 + ic) * 64 + g * 4];
                    a0 += xv * bf(w.x); a1 += xv * bf(w.y);
                    a2 += xv * bf(w.z); a3 += xv * bf(w.w);
                }
        c3[sub][oh * 64 + g * 4]     = lrelu(a0);
        c3[sub][oh * 64 + g * 4 + 1] = lrelu(a1);
        c3[sub][oh * 64 + g * 4 + 2] = lrelu(a2);
        c3[sub][oh * 64 + g * 4 + 3] = lrelu(a3);
    }
    __syncthreads();

    for (int idx = stid; idx < 64; idx += 128) {
        int oh = idx >> 5, g = idx & 31;
        float a0 = bf(wl[19056 + g * 4]), a1 = bf(wl[19057 + g * 4]),
              a2 = bf(wl[19058 + g * 4]), a3 = bf(wl[19059 + g * 4]);
#pragma unroll
        for (int ic = 0; ic < 64; ic++) {
            float xv = c3[sub][oh * 64 + ic];
            ushort4 w = *(const ushort4*)&wl[10864 + ic * 128 + g * 4];
            a0 += xv * bf(w.x); a1 += xv * bf(w.y);
            a2 += xv * bf(w.z); a3 += xv * bf(w.w);
        }
        P.featbf[bt * 256 + (g * 4 + 0) * 2 + oh] = f2b(lrelu(a0));
        P.featbf[bt * 256 + (g * 4 + 1) * 2 + oh] = f2b(lrelu(a1));
        P.featbf[bt * 256 + (g * 4 + 2) * 2 + oh] = f2b(lrelu(a2));
        P.featbf[bt * 256 + (g * 4 + 3) * 2 + oh] = f2b(lrelu(a3));
    }
}

// ================= K2: zx = featbf @ Wk + b (MFMA) ==========================
__global__ __launch_bounds__(256) void gemm_zx(
    const u16* __restrict__ Abf, const u16* __restrict__ PB,
    const void* __restrict__ bias, const int* __restrict__ flag,
    float* __restrict__ out)
{
    __shared__ __align__(16) u16 As[16 * 264];
    const int mb = blockIdx.y, nb = blockIdx.x, tid = threadIdx.x;
    const int f32 = *flag;
    const int m0 = mb * 16;
    {
        int row = tid >> 4, part = tid & 15;
        const f32x4* src = (const f32x4*)&Abf[(size_t)(m0 + row) * 256 + part * 16];
        f32x4 v0 = src[0], v1 = src[1];
        *(f32x4*)&As[row * 264 + part * 16] = v0;
        *(f32x4*)&As[row * 264 + part * 16 + 8] = v1;
    }
    __syncthreads();
    const int wv = tid >> 6, lane = tid & 63;
    const int colw = lane & 15, q = lane >> 4;
    const int n = nb * 64 + wv * 16 + colw;
    f32x4 acc = {0.f, 0.f, 0.f, 0.f};
#pragma unroll
    for (int kt = 0; kt < 8; kt++) {
        short8 a = *(const short8*)&As[colw * 264 + kt * 32 + q * 8];
        short8 b = *(const short8*)&PB[((((size_t)kt << 10) + n) * 4 + q) * 8];
        acc = __builtin_amdgcn_mfma_f32_16x16x32_bf16(a, b, acc, 0, 0, 0);
    }
    const float bj = ldf(bias, n, f32);
#pragma unroll
    for (int r = 0; r < 4; r++) {
        int row = q * 4 + r;
        out[(size_t)(m0 + row) * 1024 + n] = acc[r] + bj;
    }
}

// ================= K3: LSTM v8 — volatile-pinned VGPR tier ==================
// Volatile loads cannot be rematerialized -> the NPRE chunks must stay live in
// registers. Tiers: 18 VGPR + 7 LDS (112 KB) + 7 streamed (112 KB/step L1).
#define NPRE 18
#define NLDS 7
#define NSTR (32 - NPRE - NLDS)
__global__ __launch_bounds__(1024, 4) void lstm_kernel(
    const float* __restrict__ zx, const u16* __restrict__ PF,
    u16* __restrict__ hseqbf)
{
    __shared__ float zp[1024];
    __shared__ __align__(16) u16 h16[256];
    __shared__ u16 hist[TSEQ * 256];                 // 32 KB
    __shared__ __align__(16) int4 wlds[NLDS * 1024]; // 112 KB
    const int b = blockIdx.x, tid = threadIdx.x;
    float c = 0.f;
    const int4* Pw = (const int4*)PF;

    int4 wr[NPRE];
    {   // volatile element loads: not rematerializable -> truly register-pinned
        const volatile int* Pv = (const volatile int*)Pw;
#pragma unroll
        for (int j = 0; j < NPRE; j++) {
            int base = (j * 1024 + tid) * 4;
            wr[j].x = Pv[base + 0];
            wr[j].y = Pv[base + 1];
            wr[j].z = Pv[base + 2];
            wr[j].w = Pv[base + 3];
        }
    }
#pragma unroll
    for (int j = 0; j < NLDS; j++) wlds[j * 1024 + tid] = Pw[(NPRE + j) * 1024 + tid];
    if (tid < 256) h16[tid] = 0;
    __syncthreads();

    for (int t = 0; t < TSEQ; t++) {
        int4 ws[NSTR];
#pragma unroll
        for (int j = 0; j < NSTR; j++) ws[j] = Pw[(NPRE + NLDS + j) * 1024 + tid];
        float zxv = zx[(size_t)(b * TSEQ + t) * 1024 + tid];

        float a0 = 0.f, a1 = 0.f, a2 = 0.f, a3 = 0.f;
#pragma unroll
        for (int j = 0; j < NPRE; j++) {
            int4 hv = *(const int4*)&h16[j * 8];     // wave-uniform LDS broadcast
            a0 = dot2(hv.x, wr[j].x, a0);
            a1 = dot2(hv.y, wr[j].y, a1);
            a2 = dot2(hv.z, wr[j].z, a2);
            a3 = dot2(hv.w, wr[j].w, a3);
        }
#pragma unroll
        for (int j = 0; j < NLDS; j++) {
            int4 hv = *(const int4*)&h16[(NPRE + j) * 8];
            int4 w = wlds[j * 1024 + tid];
            a0 = dot2(hv.x, w.x, a0);
            a1 = dot2(hv.y, w.y, a1);
            a2 = dot2(hv.z, w.z, a2);
            a3 = dot2(hv.w, w.w, a3);
        }
#pragma unroll
        for (int j = 0; j < NSTR; j++) {
            int4 hv = *(const int4*)&h16[(NPRE + NLDS + j) * 8];
            a0 = dot2(hv.x, ws[j].x, a0);
            a1 = dot2(hv.y, ws[j].y, a1);
            a2 = dot2(hv.z, ws[j].z, a2);
            a3 = dot2(hv.w, ws[j].w, a3);
        }
        zp[tid] = ((a0 + a1) + (a2 + a3)) + zxv;
        __syncthreads();
        if (tid < 256) {
            float ai = zp[tid], af = zp[256 + tid], ag = zp[512 + tid], ao = zp[768 + tid];
            float ig = fsigm(ai), fg = fsigm(af), og = fsigm(ao);
            float gg = ftanh(ag);
            c = fg * c + ig * gg;
            float h = og * ftanh(c);
            h16[tid] = __builtin_bit_cast(unsigned short, (_Float16)h);
            hist[t * 256 + tid] = f2b(h);
        }
        __syncthreads();
    }
    for (int i = tid; i < TSEQ * 256; i += 1024)
        hseqbf[(size_t)b * (TSEQ * 256) + i] = hist[i];
}

// ================= K4: heads = pir (blocks 0..63) + pim =====================
__global__ __launch_bounds__(256) void heads_kernel(
    const u16* __restrict__ Abf,
    const u16* __restrict__ PBpir, const u16* __restrict__ PBpim,
    const void* __restrict__ pir_b, const void* __restrict__ v_b,
    const void* __restrict__ pim_b, const int* __restrict__ flag,
    const int* __restrict__ mask, const int* __restrict__ a_taken,
    float* __restrict__ entpir, float* __restrict__ ppira, float* __restrict__ vpred,
    float* __restrict__ partS, float* __restrict__ partU, float* __restrict__ za)
{
    __shared__ __align__(16) u16 As[64 * 264];
    __shared__ float redS[4][16], redU[4][16];
    const int tid = threadIdx.x;
    const int wv = tid >> 6, lane = tid & 63;
    const int colw = lane & 15, q = lane >> 4;
    const int f32 = *flag;

    if (blockIdx.x < 64) {
        const int m0 = blockIdx.x * 64;
        for (int idx = tid; idx < 1024; idx += 256) {
            int row = idx >> 4, part = idx & 15;
            const f32x4* src = (const f32x4*)&Abf[(size_t)(m0 + row) * 256 + part * 16];
            f32x4 v0 = src[0], v1 = src[1];
            *(f32x4*)&As[row * 264 + part * 16] = v0;
            *(f32x4*)&As[row * 264 + part * 16 + 8] = v1;
        }
        __syncthreads();
        f32x4 acc[4];
#pragma unroll
        for (int nt = 0; nt < 4; nt++) acc[nt] = (f32x4){0.f, 0.f, 0.f, 0.f};
#pragma unroll
        for (int kt = 0; kt < 8; kt++) {
            short8 a = *(const short8*)&As[(wv * 16 + colw) * 264 + kt * 32 + q * 8];
#pragma unroll
            for (int nt = 0; nt < 4; nt++) {
                short8 b = *(const short8*)&PBpir[((((size_t)kt * 64) + nt * 16 + colw) * 4 + q) * 8];
                acc[nt] = __builtin_amdgcn_mfma_f32_16x16x32_bf16(a, b, acc[nt], 0, 0, 0);
            }
        }
        float* zq = (float*)&As[wv * 4224];
#pragma unroll
        for (int nt = 0; nt < 4; nt++) {
            int col = nt * 16 + colw;
            float bj = (col < 36) ? ldf(pir_b, col, f32)
                                  : (col == 36 ? ldf(v_b, 0, f32) : 0.f);
#pragma unroll
            for (int r = 0; r < 4; r++)
                zq[(q * 4 + r) * 65 + col] = acc[nt][r] + bj;
        }
        if (lane < 16) {
            int R = m0 + wv * 16 + lane;
            const float* zrow = &zq[lane * 65];
            float Z = 0.f, U = 0.f;
            for (int cc = 0; cc < 36; cc++) {
                float z = zrow[cc];
                float ev = __expf(z);
                Z += ev; U += ev * z;
            }
            entpir[R] = logf(Z) - U / Z;
            ppira[R]  = __expf(zrow[a_taken[R]]) / Z;
            vpred[R]  = zrow[36];
        }
        return;
    }
    const int b2 = blockIdx.x - 64;
    const int nb = b2 & 63, mb = b2 >> 6;
    const int m0 = mb * 16;
    {
        int row = tid >> 4, part = tid & 15;
        const f32x4* src = (const f32x4*)&Abf[(size_t)(m0 + row) * 256 + part * 16];
        f32x4 v0 = src[0], v1 = src[1];
        *(f32x4*)&As[row * 264 + part * 16] = v0;
        *(f32x4*)&As[row * 264 + part * 16 + 8] = v1;
    }
    __syncthreads();
    const int n = nb * 64 + wv * 16 + colw;
    f32x4 acc = {0.f, 0.f, 0.f, 0.f};
#pragma unroll
    for (int kt = 0; kt < 8; kt++) {
        short8 a = *(const short8*)&As[colw * 264 + kt * 32 + q * 8];
        short8 b = *(const short8*)&PBpim[((((size_t)kt << 12) + n) * 4 + q) * 8];
        acc = __builtin_amdgcn_mfma_f32_16x16x32_bf16(a, b, acc, 0, 0, 0);
    }
    const float bj = ldf(pim_b, n, f32);
    float sv[4], uv[4];
#pragma unroll
    for (int r = 0; r < 4; r++) {
        int row = m0 + q * 4 + r;
        float z = acc[r] + bj;
        int mm = mask[(size_t)row * 4096 + n];
        float ev = __expf(z);
        sv[r] = mm ? ev : 0.f;
        uv[r] = mm ? ev * z : 0.f;
        if (n == a_taken[row]) za[row] = z;
    }
#pragma unroll
    for (int r = 0; r < 4; r++) {
        for (int off = 1; off < 16; off <<= 1) {
            sv[r] += __shfl_xor(sv[r], off, 16);
            uv[r] += __shfl_xor(uv[r], off, 16);
        }
        if (colw == 0) { redS[wv][q * 4 + r] = sv[r]; redU[wv][q * 4 + r] = uv[r]; }
    }
    __syncthreads();
    if (tid < 16) {
        float S = redS[0][tid] + redS[1][tid] + redS[2][tid] + redS[3][tid];
        float U = redU[0][tid] + redU[1][tid] + redU[2][tid] + redU[3][tid];
        partS[(size_t)(m0 + tid) * 64 + nb] = S;
        partU[(size_t)(m0 + tid) * 64 + nb] = U;
    }
}

// ================= K5: tail = pimfin + gae + pg + vf + fin (ticket) =========
#define TAIL_BLOCKS (16 + 256)
__global__ __launch_bounds__(256) void tail_kernel(
    const float* __restrict__ partS, const float* __restrict__ partU,
    const float* __restrict__ za,
    const float* __restrict__ entpir, const float* __restrict__ ppira,
    const float* __restrict__ vpred,
    const void* __restrict__ lgold, const void* __restrict__ gae,
    const void* __restrict__ ovp, const void* __restrict__ ret,
    float* __restrict__ scal, const int* __restrict__ flag,
    void* __restrict__ out)
{
    const int bid = blockIdx.x, tid = threadIdx.x;
    const int f32 = *flag;
    __shared__ float sh[8];
    __shared__ float mst[2];
    if (bid < 16) {
        const int r = bid * 256 + tid;
        float S = 0.f, U = 0.f;
#pragma unroll
        for (int t2 = 0; t2 < 64; t2++) {
            S += partS[(size_t)r * 64 + t2];
            U += partU[(size_t)r * 64 + t2];
        }
        float entpim = logf(S) - U / S;
        float ppima = __expf(za[r]) / S;
        float s = 0.f, s2 = 0.f;
        if (f32) {
            const float* gp = (const float*)gae;
            for (int i = tid; i < BT; i += 256) { float v = gp[i]; s += v; s2 += v * v; }
        } else {
            const u16* gp = (const u16*)gae;
            for (int i = tid; i < BT; i += 256) { float v = bf(gp[i]); s += v; s2 += v * v; }
        }
        for (int off = 32; off; off >>= 1) {
            s += __shfl_down(s, off, 64); s2 += __shfl_down(s2, off, 64);
        }
        if ((tid & 63) == 0) { sh[tid >> 6] = s; sh[4 + (tid >> 6)] = s2; }
        __syncthreads();
        if (tid == 0) {
            float Sa = sh[0] + sh[1] + sh[2] + sh[3];
            float S2a = sh[4] + sh[5] + sh[6] + sh[7];
            float mean = Sa / (float)BT;
            float var = S2a / (float)BT - mean * mean;
            mst[0] = mean; mst[1] = sqrtf(fmaxf(var, 0.f));
        }
        __syncthreads();
        float mean = mst[0], sd = mst[1];
        float p = (r & 1) ? ppima : ppira[r];
        float ln = logf(p);
        float rt = __expf(ln - ldf(lgold, r, f32));
        float g = (ldf(gae, r, f32) - mean) / (sd + 1e-8f);
        float rtc = fminf(fmaxf(rt, 0.8f), 1.2f);
        float pg = fmaxf(-g * rt, -g * rtc);
        float e12 = entpir[r] + entpim;
        for (int off = 32; off; off >>= 1) {
            pg += __shfl_down(pg, off, 64);
            e12 += __shfl_down(e12, off, 64);
        }
        if ((tid & 63) == 0) {
            atomicAdd(&scal[2], pg);
            atomicAdd(&scal[3], e12);
        }
    } else {
        // vf: dtype-specialized loops (no per-element select)
        const int i0 = (bid - 16) * 16;
        float s = 0.f;
        if (f32) {
            const float* rp = (const float*)ret;
            const float* op = (const float*)ovp;
            for (int rr = 0; rr < 16; rr++) {
                float vp = vpred[i0 + rr];
                for (int j = tid; j < BT; j += 256) {
                    float r2 = rp[j], o = op[j];
                    float d = fminf(fmaxf(vp - o, -0.2f), 0.2f);
                    float v1 = vp - r2;    v1 *= v1;
                    float v2 = o + d - r2; v2 *= v2;
                    s += fmaxf(v1, v2);
                }
            }
        } else {
            const u16* rp = (const u16*)ret;
            const u16* op = (const u16*)ovp;
            for (int rr = 0; rr < 16; rr++) {
                float vp = vpred[i0 + rr];
                for (int j = tid; j < BT; j += 256) {
                    float r2 = bf(rp[j]), o = bf(op[j]);
                    float d = fminf(fmaxf(vp - o, -0.2f), 0.2f);
                    float v1 = vp - r2;    v1 *= v1;
                    float v2 = o + d - r2; v2 *= v2;
                    s += fmaxf(v1, v2);
                }
            }
        }
        for (int off = 32; off; off >>= 1) s += __shfl_down(s, off, 64);
        if ((tid & 63) == 0) sh[tid >> 6] = s;
        __syncthreads();
        if (tid == 0) atomicAdd(&scal[5], sh[0] + sh[1] + sh[2] + sh[3]);
    }
    __threadfence();
    __syncthreads();
    if (tid == 0) {
        unsigned old = atomicAdd((unsigned int*)&scal[8], 1u);
        if (old == TAIL_BLOCKS - 1) {
            __threadfence();
            float pgs = atomicAdd(&scal[2], 0.f);
            float ents = atomicAdd(&scal[3], 0.f);
            float vfs = atomicAdd(&scal[5], 0.f);
            float pg = pgs / (float)BT;
            float vf = 0.5f * vfs / ((float)BT * (float)BT);
            float loss = pg - ents + vf;
            if (f32) {
                float* o = (float*)out;
                o[0] = loss; o[1] = pg; o[2] = ents; o[3] = vf;
            } else {
                u16* o = (u16*)out;
                o[0] = f2b(loss); o[1] = f2b(pg); o[2] = f2b(ents); o[3] = f2b(vf);
            }
        }
    }
}

extern "C" void kernel_launch(void* const* d_in, const int* in_sizes, int n_in,
                              void* d_out, int out_size, void* d_ws, size_t ws_size,
                              hipStream_t stream)
{
    const int* mask = (const int*)d_in[1];
    const int* a_tk = (const int*)d_in[3];

    float* p = (float*)d_ws;
    u16*   featbf = (u16*)p;            p += 524288;    // 1M u16
    float* zx     = p;                  p += 4194304;   // 16 MB
    u16*   hseqbf = (u16*)p;            p += 524288;    // 1M u16
    u16*   PF     = (u16*)p;            p += 131072;    // f16 Wr
    u16*   PBk    = (u16*)p;            p += 131072;    // bf16 Wk frag
    u16*   PBpim  = (u16*)p;            p += 524288;    // bf16 pimW frag
    u16*   PBpir  = (u16*)p;            p += 8192;      // bf16 [pirW|vW] frag
    float* scal   = p;                  p += 32;
    int*   flag   = (int*)p;            p += 4;
    float* partS  = p;                  p += 262144;
    float* partU  = p;                  p += 262144;
    float* za     = p;                  p += 4096;
    float* entpir = p;                  p += 4096;
    float* ppira  = p;                  p += 4096;
    float* vpred  = p;                  p += 4096;

    PrepPtrs P;
    P.x = d_in[0];
    P.W1 = d_in[7];  P.b1 = d_in[8];
    P.W2 = d_in[9];  P.b2 = d_in[10];
    P.W3 = d_in[11]; P.b3 = d_in[12];
    P.W4 = d_in[13]; P.b4 = d_in[14];
    P.Wk = d_in[15]; P.Wr = d_in[16];
    P.Wpir = d_in[18]; P.Wpim = d_in[20]; P.Wv = d_in[22];
    P.probe = (const u16*)d_in[15];
    P.featbf = featbf; P.PF = PF; P.PBk = PBk; P.PBpim = PBpim; P.PBpir = PBpir;
    P.scal = scal; P.flag = flag;

    prep_kernel<<<PACK_BLKS + CONV_BLKS, 256, 0, stream>>>(P);
    gemm_zx<<<dim3(16, 256), 256, 0, stream>>>(featbf, PBk, d_in[17], flag, zx);
    lstm_kernel<<<NB, 1024, 0, stream>>>(zx, PF, hseqbf);
    heads_kernel<<<64 + 64 * 256, 256, 0, stream>>>(
        hseqbf, PBpir, PBpim, d_in[19], d_in[23], d_in[21], flag, mask, a_tk,
        entpir, ppira, vpred, partS, partU, za);
    tail_kernel<<<TAIL_BLOCKS, 256, 0, stream>>>(
        partS, partU, za, entpir, ppira, vpred,
        d_in[2], d_in[4], d_in[5], d_in[6], scal, flag, (void*)d_out);
}

// Round 12
// 516.154 us; speedup vs baseline: 1.1173x; 1.1173x over previous
//
#include <hip/hip_runtime.h>

typedef unsigned short u16;
typedef unsigned int   u32;

#define BT   4096
#define TSEQ 64
#define NB   64

typedef __attribute__((ext_vector_type(8))) short  short8;
typedef __attribute__((ext_vector_type(4))) float  f32x4;
typedef __attribute__((ext_vector_type(2))) _Float16 h2;

__device__ __forceinline__ float bf(u16 v) {
    u32 u = ((u32)v) << 16;
    return __builtin_bit_cast(float, u);
}
__device__ __forceinline__ u16 f2b(float f) {
    u32 u = __builtin_bit_cast(u32, f);
    return (u16)((u + 0x7fffu + ((u >> 16) & 1u)) >> 16);  // RNE
}
__device__ __forceinline__ float lrelu(float x) { return x > 0.f ? x : 0.2f * x; }
__device__ __forceinline__ h2 i2h(int v) { return __builtin_bit_cast(h2, v); }
__device__ __forceinline__ float dot2(int hbits, int wbits, float acc) {
#if __has_builtin(__builtin_amdgcn_fdot2)
    return __builtin_amdgcn_fdot2(i2h(hbits), i2h(wbits), acc, false);
#else
    h2 a = i2h(hbits), b = i2h(wbits);
    return acc + (float)a.x * (float)b.x + (float)a.y * (float)b.y;
#endif
}
__device__ __forceinline__ float fsigm(float x) { return 1.f / (1.f + __expf(-x)); }
__device__ __forceinline__ float ftanh(float x) { return 1.f - 2.f / (__expf(2.f * x) + 1.f); }
__device__ __forceinline__ float ldf(const void* p, int i, int f32) {
    return f32 ? ((const float*)p)[i] : bf(((const u16*)p)[i]);
}
__device__ __forceinline__ u16 ldb(const void* p, int i, int f32) {
    return f32 ? f2b(((const float*)p)[i]) : ((const u16*)p)[i];
}

struct PrepPtrs {
    const void *x, *W1, *b1, *W2, *b2, *W3, *b3, *W4, *b4;
    const void *Wr, *Wk, *Wpim, *Wpir, *Wv;
    const u16* probe;
    u16 *featbf, *PF, *PBk, *PBpim, *PBpir;
    float* scal; int* flag;
};

#define PACK_BLKS 6208
#define CONV_BLKS 2048   // 2 images per block

// ================= K1: prep = sniff(inline) + pack + conv ===================
__global__ __launch_bounds__(256) void prep_kernel(PrepPtrs P)
{
    const int bid = blockIdx.x, tid = threadIdx.x;
    const int lane = tid & 63;
    u16 pv = P.probe[2 * lane];
    int e = (pv >> 7) & 0xFF;
    unsigned long long m = __ballot(pv == 0 || (e >= 100 && e <= 130));
    const int f32 = (__popcll(m) < 48) ? 1 : 0;

    if (bid == 0 && tid < 32) { P.scal[tid] = 0.f; if (tid == 0) *P.flag = f32; }

    if (bid < PACK_BLKS) {
        const int blk = bid;
        if (blk < 1024) {
            int gid = blk * 256 + tid;
            int k = gid >> 10, col = gid & 1023;
            float f = ldf(P.Wr, gid, f32);
            _Float16 h = (_Float16)f;
            P.PF[((size_t)(k >> 3) * 1024 + col) * 8 + (k & 7)] =
                __builtin_bit_cast(unsigned short, h);
        } else if (blk < 2048) {
            int gid = (blk - 1024) * 256 + tid;
            int k = gid >> 10, col = gid & 1023;
            P.PBk[((((size_t)(k >> 5) << 10) + col) * 4 + ((k >> 3) & 3)) * 8 + (k & 7)] =
                ldb(P.Wk, gid, f32);
        } else if (blk < 6144) {
            int gid = (blk - 2048) * 256 + tid;
            int k = gid >> 12, col = gid & 4095;
            P.PBpim[((((size_t)(k >> 5) << 12) + col) * 4 + ((k >> 3) & 3)) * 8 + (k & 7)] =
                ldb(P.Wpim, gid, f32);
        } else {
            int gid = (blk - 6144) * 256 + tid;   // 16384: 256 k x 64 cols
            int k = gid >> 6, col = gid & 63;
            u16 v = 0;
            if (col < 36)      v = ldb(P.Wpir, k * 36 + col, f32);
            else if (col == 36) v = ldb(P.Wv, k, f32);
            P.PBpir[(((size_t)(k >> 5) * 64 + col) * 4 + ((k >> 3) & 3)) * 8 + (k & 7)] = v;
        }
        return;
    }

    // ---- conv branch: 2 images per block; LDS-staged bf16 weights ----
    __shared__ __align__(16) u16 wl[19184];
    __shared__ float xs[2][832];
    __shared__ float c1[2][384];
    __shared__ float c2[2][480];
    __shared__ float c3[2][128];
    const int pair = bid - PACK_BLKS;
    const int sub = tid >> 7, stid = tid & 127;
    const int bt = pair * 2 + sub;

    {
        const void* sp[8] = {P.W1, P.b1, P.W2, P.b2, P.W3, P.b3, P.W4, P.b4};
        const int   sn[8] = {512, 16, 2048, 32, 8192, 64, 8192, 128};
        int o = 0;
        for (int s = 0; s < 8; s++) {
            for (int i = tid; i < sn[s]; i += 256) wl[o + i] = ldb(sp[s], i, f32);
            o += sn[s];
        }
    }
    for (int i = stid; i < 832; i += 128) xs[sub][i] = ldf(P.x, bt * 832 + i, f32);
    __syncthreads();

    for (int idx = stid; idx < 96; idx += 128) {
        int pos = idx >> 2, g = idx & 3;
        int oh = pos >> 2, ow = pos & 3;
        float a0 = bf(wl[512 + g * 4]), a1 = bf(wl[513 + g * 4]),
              a2 = bf(wl[514 + g * 4]), a3 = bf(wl[515 + g * 4]);
        for (int kh = 0; kh < 2; kh++)
            for (int kw = 0; kw < 2; kw++)
#pragma unroll
                for (int ic = 0; ic < 8; ic++) {
                    float xv = xs[sub][(2 * oh + kh) * 64 + (2 * ow + kw) * 8 + ic];
                    ushort4 w = *(const ushort4*)&wl[((kh * 2 + kw) * 8 + ic) * 16 + g * 4];
                    a0 += xv * bf(w.x); a1 += xv * bf(w.y);
                    a2 += xv * bf(w.z); a3 += xv * bf(w.w);
                }
        c1[sub][pos * 16 + g * 4]     = lrelu(a0);
        c1[sub][pos * 16 + g * 4 + 1] = lrelu(a1);
        c1[sub][pos * 16 + g * 4 + 2] = lrelu(a2);
        c1[sub][pos * 16 + g * 4 + 3] = lrelu(a3);
    }
    __syncthreads();

    for (int idx = stid; idx < 120; idx += 128) {
        int pos = idx >> 3, g = idx & 7;
        int oh = pos / 3, ow = pos % 3;
        float a0 = bf(wl[2576 + g * 4]), a1 = bf(wl[2577 + g * 4]),
              a2 = bf(wl[2578 + g * 4]), a3 = bf(wl[2579 + g * 4]);
        for (int kh = 0; kh < 2; kh++)
            for (int kw = 0; kw < 2; kw++)
#pragma unroll
                for (int ic = 0; ic < 16; ic++) {
                    float xv = c1[sub][((oh + kh) * 4 + (ow + kw)) * 16 + ic];
                    ushort4 w = *(const ushort4*)&wl[528 + ((kh * 2 + kw) * 16 + ic) * 32 + g * 4];
                    a0 += xv * bf(w.x); a1 += xv * bf(w.y);
                    a2 += xv * bf(w.z); a3 += xv * bf(w.w);
                }
        c2[sub][pos * 32 + g * 4]     = lrelu(a0);
        c2[sub][pos * 32 + g * 4 + 1] = lrelu(a1);
        c2[sub][pos * 32 + g * 4 + 2] = lrelu(a2);
        c2[sub][pos * 32 + g * 4 + 3] = lrelu(a3);
    }
    __syncthreads();

    for (int idx = stid; idx < 32; idx += 128) {
        int oh = idx >> 4, g = idx & 15;
        float a0 = bf(wl[10800 + g * 4]), a1 = bf(wl[10801 + g * 4]),
              a2 = bf(wl[10802 + g * 4]), a3 = bf(wl[10803 + g * 4]);
        for (int kh = 0; kh < 2; kh++)
            for (int kw = 0; kw < 2; kw++)
#pragma unroll
                for (int ic = 0; ic < 32; ic++) {
                    float xv = c2[sub][((2 * oh + kh) * 3 + kw) * 32 + ic];
                    ushort4 w = *(const ushort4*)&wl[2608 + ((kh * 2 + kw) * 32 + ic) * 64 + g * 4];
                    a0 += xv * bf(w.x); a1 += xv * bf(w.y);
                    a2 += xv * bf(w.z); a3 += xv * bf(w.w);
                }
        c3[sub][oh * 64 + g * 4]     = lrelu(a0);
        c3[sub][oh * 64 + g * 4 + 1] = lrelu(a1);
        c3[sub][oh * 64 + g * 4 + 2] = lrelu(a2);
        c3[sub][oh * 64 + g * 4 + 3] = lrelu(a3);
    }
    __syncthreads();

    for (int idx = stid; idx < 64; idx += 128) {
        int oh = idx >> 5, g = idx & 31;
        float a0 = bf(wl[19056 + g * 4]), a1 = bf(wl[19057 + g * 4]),
              a2 = bf(wl[19058 + g * 4]), a3 = bf(wl[19059 + g * 4]);
#pragma unroll
        for (int ic = 0; ic < 64; ic++) {
            float xv = c3[sub][oh * 64 + ic];
            ushort4 w = *(const ushort4*)&wl[10864 + ic * 128 + g * 4];
            a0 += xv * bf(w.x); a1 += xv * bf(w.y);
            a2 += xv * bf(w.z); a3 += xv * bf(w.w);
        }
        P.featbf[bt * 256 + (g * 4 + 0) * 2 + oh] = f2b(lrelu(a0));
        P.featbf[bt * 256 + (g * 4 + 1) * 2 + oh] = f2b(lrelu(a1));
        P.featbf[bt * 256 + (g * 4 + 2) * 2 + oh] = f2b(lrelu(a2));
        P.featbf[bt * 256 + (g * 4 + 3) * 2 + oh] = f2b(lrelu(a3));
    }
}

// ================= K2: zx = featbf @ Wk + b (MFMA) ==========================
__global__ __launch_bounds__(256) void gemm_zx(
    const u16* __restrict__ Abf, const u16* __restrict__ PB,
    const void* __restrict__ bias, const int* __restrict__ flag,
    float* __restrict__ out)
{
    __shared__ __align__(16) u16 As[16 * 264];
    const int mb = blockIdx.y, nb = blockIdx.x, tid = threadIdx.x;
    const int f32 = *flag;
    const int m0 = mb * 16;
    {
        int row = tid >> 4, part = tid & 15;
        const f32x4* src = (const f32x4*)&Abf[(size_t)(m0 + row) * 256 + part * 16];
        f32x4 v0 = src[0], v1 = src[1];
        *(f32x4*)&As[row * 264 + part * 16] = v0;
        *(f32x4*)&As[row * 264 + part * 16 + 8] = v1;
    }
    __syncthreads();
    const int wv = tid >> 6, lane = tid & 63;
    const int colw = lane & 15, q = lane >> 4;
    const int n = nb * 64 + wv * 16 + colw;
    f32x4 acc = {0.f, 0.f, 0.f, 0.f};
#pragma unroll
    for (int kt = 0; kt < 8; kt++) {
        short8 a = *(const short8*)&As[colw * 264 + kt * 32 + q * 8];
        short8 b = *(const short8*)&PB[((((size_t)kt << 10) + n) * 4 + q) * 8];
        acc = __builtin_amdgcn_mfma_f32_16x16x32_bf16(a, b, acc, 0, 0, 0);
    }
    const float bj = ldf(bias, n, f32);
#pragma unroll
    for (int r = 0; r < 4; r++) {
        int row = q * 4 + r;
        out[(size_t)(m0 + row) * 1024 + n] = acc[r] + bj;
    }
}

// ================= K3: LSTM v9 — waves_per_eu(4,4) unlocks 128-VGPR budget ==
// __launch_bounds__ only sets MIN waves/EU; the allocator still targeted 8
// waves (64 VGPR) and rematerialized/spilled every preload (R8-R11). Setting
// max=4 tells it occupancy >4 waves/EU is impossible -> free to use 128 VGPRs
// -> the 18 preloaded chunks (72 VGPRs) stay genuinely register-resident.
#define NPRE 18
#define NLDS 7
#define NSTR (32 - NPRE - NLDS)
__global__ __launch_bounds__(1024)
__attribute__((amdgpu_waves_per_eu(4, 4)))
void lstm_kernel(
    const float* __restrict__ zx, const u16* __restrict__ PF,
    u16* __restrict__ hseqbf)
{
    __shared__ float zp[1024];
    __shared__ __align__(16) u16 h16[256];
    __shared__ u16 hist[TSEQ * 256];                 // 32 KB
    __shared__ __align__(16) int4 wlds[NLDS * 1024]; // 112 KB
    const int b = blockIdx.x, tid = threadIdx.x;
    float c = 0.f;
    const int4* Pw = (const int4*)PF;

    int4 wr[NPRE];
#pragma unroll
    for (int j = 0; j < NPRE; j++) wr[j] = Pw[j * 1024 + tid];
#pragma unroll
    for (int j = 0; j < NLDS; j++) wlds[j * 1024 + tid] = Pw[(NPRE + j) * 1024 + tid];
    if (tid < 256) h16[tid] = 0;
    __syncthreads();

    for (int t = 0; t < TSEQ; t++) {
        int4 ws[NSTR];
#pragma unroll
        for (int j = 0; j < NSTR; j++) ws[j] = Pw[(NPRE + NLDS + j) * 1024 + tid];
        float zxv = zx[(size_t)(b * TSEQ + t) * 1024 + tid];

        float a0 = 0.f, a1 = 0.f, a2 = 0.f, a3 = 0.f;
#pragma unroll
        for (int j = 0; j < NPRE; j++) {
            int4 hv = *(const int4*)&h16[j * 8];     // wave-uniform LDS broadcast
            a0 = dot2(hv.x, wr[j].x, a0);
            a1 = dot2(hv.y, wr[j].y, a1);
            a2 = dot2(hv.z, wr[j].z, a2);
            a3 = dot2(hv.w, wr[j].w, a3);
        }
#pragma unroll
        for (int j = 0; j < NLDS; j++) {
            int4 hv = *(const int4*)&h16[(NPRE + j) * 8];
            int4 w = wlds[j * 1024 + tid];
            a0 = dot2(hv.x, w.x, a0);
            a1 = dot2(hv.y, w.y, a1);
            a2 = dot2(hv.z, w.z, a2);
            a3 = dot2(hv.w, w.w, a3);
        }
#pragma unroll
        for (int j = 0; j < NSTR; j++) {
            int4 hv = *(const int4*)&h16[(NPRE + NLDS + j) * 8];
            a0 = dot2(hv.x, ws[j].x, a0);
            a1 = dot2(hv.y, ws[j].y, a1);
            a2 = dot2(hv.z, ws[j].z, a2);
            a3 = dot2(hv.w, ws[j].w, a3);
        }
        zp[tid] = ((a0 + a1) + (a2 + a3)) + zxv;
        __syncthreads();
        if (tid < 256) {
            float ai = zp[tid], af = zp[256 + tid], ag = zp[512 + tid], ao = zp[768 + tid];
            float ig = fsigm(ai), fg = fsigm(af), og = fsigm(ao);
            float gg = ftanh(ag);
            c = fg * c + ig * gg;
            float h = og * ftanh(c);
            h16[tid] = __builtin_bit_cast(unsigned short, (_Float16)h);
            hist[t * 256 + tid] = f2b(h);
        }
        __syncthreads();
    }
    for (int i = tid; i < TSEQ * 256; i += 1024)
        hseqbf[(size_t)b * (TSEQ * 256) + i] = hist[i];
}

// ================= K4: heads = pir (blocks 0..63) + pim =====================
__global__ __launch_bounds__(256) void heads_kernel(
    const u16* __restrict__ Abf,
    const u16* __restrict__ PBpir, const u16* __restrict__ PBpim,
    const void* __restrict__ pir_b, const void* __restrict__ v_b,
    const void* __restrict__ pim_b, const int* __restrict__ flag,
    const int* __restrict__ mask, const int* __restrict__ a_taken,
    float* __restrict__ entpir, float* __restrict__ ppira, float* __restrict__ vpred,
    float* __restrict__ partS, float* __restrict__ partU, float* __restrict__ za)
{
    __shared__ __align__(16) u16 As[64 * 264];
    __shared__ float redS[4][16], redU[4][16];
    const int tid = threadIdx.x;
    const int wv = tid >> 6, lane = tid & 63;
    const int colw = lane & 15, q = lane >> 4;
    const int f32 = *flag;

    if (blockIdx.x < 64) {
        const int m0 = blockIdx.x * 64;
        for (int idx = tid; idx < 1024; idx += 256) {
            int row = idx >> 4, part = idx & 15;
            const f32x4* src = (const f32x4*)&Abf[(size_t)(m0 + row) * 256 + part * 16];
            f32x4 v0 = src[0], v1 = src[1];
            *(f32x4*)&As[row * 264 + part * 16] = v0;
            *(f32x4*)&As[row * 264 + part * 16 + 8] = v1;
        }
        __syncthreads();
        f32x4 acc[4];
#pragma unroll
        for (int nt = 0; nt < 4; nt++) acc[nt] = (f32x4){0.f, 0.f, 0.f, 0.f};
#pragma unroll
        for (int kt = 0; kt < 8; kt++) {
            short8 a = *(const short8*)&As[(wv * 16 + colw) * 264 + kt * 32 + q * 8];
#pragma unroll
            for (int nt = 0; nt < 4; nt++) {
                short8 b = *(const short8*)&PBpir[((((size_t)kt * 64) + nt * 16 + colw) * 4 + q) * 8];
                acc[nt] = __builtin_amdgcn_mfma_f32_16x16x32_bf16(a, b, acc[nt], 0, 0, 0);
            }
        }
        float* zq = (float*)&As[wv * 4224];
#pragma unroll
        for (int nt = 0; nt < 4; nt++) {
            int col = nt * 16 + colw;
            float bj = (col < 36) ? ldf(pir_b, col, f32)
                                  : (col == 36 ? ldf(v_b, 0, f32) : 0.f);
#pragma unroll
            for (int r = 0; r < 4; r++)
                zq[(q * 4 + r) * 65 + col] = acc[nt][r] + bj;
        }
        if (lane < 16) {
            int R = m0 + wv * 16 + lane;
            const float* zrow = &zq[lane * 65];
            float Z = 0.f, U = 0.f;
            for (int cc = 0; cc < 36; cc++) {
                float z = zrow[cc];
                float ev = __expf(z);
                Z += ev; U += ev * z;
            }
            entpir[R] = logf(Z) - U / Z;
            ppira[R]  = __expf(zrow[a_taken[R]]) / Z;
            vpred[R]  = zrow[36];
        }
        return;
    }
    const int b2 = blockIdx.x - 64;
    const int nb = b2 & 63, mb = b2 >> 6;
    const int m0 = mb * 16;
    {
        int row = tid >> 4, part = tid & 15;
        const f32x4* src = (const f32x4*)&Abf[(size_t)(m0 + row) * 256 + part * 16];
        f32x4 v0 = src[0], v1 = src[1];
        *(f32x4*)&As[row * 264 + part * 16] = v0;
        *(f32x4*)&As[row * 264 + part * 16 + 8] = v1;
    }
    __syncthreads();
    const int n = nb * 64 + wv * 16 + colw;
    f32x4 acc = {0.f, 0.f, 0.f, 0.f};
#pragma unroll
    for (int kt = 0; kt < 8; kt++) {
        short8 a = *(const short8*)&As[colw * 264 + kt * 32 + q * 8];
        short8 b = *(const short8*)&PBpim[((((size_t)kt << 12) + n) * 4 + q) * 8];
        acc = __builtin_amdgcn_mfma_f32_16x16x32_bf16(a, b, acc, 0, 0, 0);
    }
    const float bj = ldf(pim_b, n, f32);
    float sv[4], uv[4];
#pragma unroll
    for (int r = 0; r < 4; r++) {
        int row = m0 + q * 4 + r;
        float z = acc[r] + bj;
        int mm = mask[(size_t)row * 4096 + n];
        float ev = __expf(z);
        sv[r] = mm ? ev : 0.f;
        uv[r] = mm ? ev * z : 0.f;
        if (n == a_taken[row]) za[row] = z;
    }
#pragma unroll
    for (int r = 0; r < 4; r++) {
        for (int off = 1; off < 16; off <<= 1) {
            sv[r] += __shfl_xor(sv[r], off, 16);
            uv[r] += __shfl_xor(uv[r], off, 16);
        }
        if (colw == 0) { redS[wv][q * 4 + r] = sv[r]; redU[wv][q * 4 + r] = uv[r]; }
    }
    __syncthreads();
    if (tid < 16) {
        float S = redS[0][tid] + redS[1][tid] + redS[2][tid] + redS[3][tid];
        float U = redU[0][tid] + redU[1][tid] + redU[2][tid] + redU[3][tid];
        partS[(size_t)(m0 + tid) * 64 + nb] = S;
        partU[(size_t)(m0 + tid) * 64 + nb] = U;
    }
}

// ================= K5: tail = pimfin + gae + pg + vf + fin (ticket) =========
#define TAIL_BLOCKS (16 + 256)
__global__ __launch_bounds__(256) void tail_kernel(
    const float* __restrict__ partS, const float* __restrict__ partU,
    const float* __restrict__ za,
    const float* __restrict__ entpir, const float* __restrict__ ppira,
    const float* __restrict__ vpred,
    const void* __restrict__ lgold, const void* __restrict__ gae,
    const void* __restrict__ ovp, const void* __restrict__ ret,
    float* __restrict__ scal, const int* __restrict__ flag,
    void* __restrict__ out)
{
    const int bid = blockIdx.x, tid = threadIdx.x;
    const int f32 = *flag;
    __shared__ float sh[8];
    __shared__ float mst[2];
    if (bid < 16) {
        const int r = bid * 256 + tid;
        float S = 0.f, U = 0.f;
#pragma unroll
        for (int t2 = 0; t2 < 64; t2++) {
            S += partS[(size_t)r * 64 + t2];
            U += partU[(size_t)r * 64 + t2];
        }
        float entpim = logf(S) - U / S;
        float ppima = __expf(za[r]) / S;
        float s = 0.f, s2 = 0.f;
        if (f32) {
            const float* gp = (const float*)gae;
            for (int i = tid; i < BT; i += 256) { float v = gp[i]; s += v; s2 += v * v; }
        } else {
            const u16* gp = (const u16*)gae;
            for (int i = tid; i < BT; i += 256) { float v = bf(gp[i]); s += v; s2 += v * v; }
        }
        for (int off = 32; off; off >>= 1) {
            s += __shfl_down(s, off, 64); s2 += __shfl_down(s2, off, 64);
        }
        if ((tid & 63) == 0) { sh[tid >> 6] = s; sh[4 + (tid >> 6)] = s2; }
        __syncthreads();
        if (tid == 0) {
            float Sa = sh[0] + sh[1] + sh[2] + sh[3];
            float S2a = sh[4] + sh[5] + sh[6] + sh[7];
            float mean = Sa / (float)BT;
            float var = S2a / (float)BT - mean * mean;
            mst[0] = mean; mst[1] = sqrtf(fmaxf(var, 0.f));
        }
        __syncthreads();
        float mean = mst[0], sd = mst[1];
        float p = (r & 1) ? ppima : ppira[r];
        float ln = logf(p);
        float rt = __expf(ln - ldf(lgold, r, f32));
        float g = (ldf(gae, r, f32) - mean) / (sd + 1e-8f);
        float rtc = fminf(fmaxf(rt, 0.8f), 1.2f);
        float pg = fmaxf(-g * rt, -g * rtc);
        float e12 = entpir[r] + entpim;
        for (int off = 32; off; off >>= 1) {
            pg += __shfl_down(pg, off, 64);
            e12 += __shfl_down(e12, off, 64);
        }
        if ((tid & 63) == 0) {
            atomicAdd(&scal[2], pg);
            atomicAdd(&scal[3], e12);
        }
    } else {
        const int i0 = (bid - 16) * 16;
        float s = 0.f;
        if (f32) {
            const float* rp = (const float*)ret;
            const float* op = (const float*)ovp;
            for (int rr = 0; rr < 16; rr++) {
                float vp = vpred[i0 + rr];
                for (int j = tid; j < BT; j += 256) {
                    float r2 = rp[j], o = op[j];
                    float d = fminf(fmaxf(vp - o, -0.2f), 0.2f);
                    float v1 = vp - r2;    v1 *= v1;
                    float v2 = o + d - r2; v2 *= v2;
                    s += fmaxf(v1, v2);
                }
            }
        } else {
            const u16* rp = (const u16*)ret;
            const u16* op = (const u16*)ovp;
            for (int rr = 0; rr < 16; rr++) {
                float vp = vpred[i0 + rr];
                for (int j = tid; j < BT; j += 256) {
                    float r2 = bf(rp[j]), o = bf(op[j]);
                    float d = fminf(fmaxf(vp - o, -0.2f), 0.2f);
                    float v1 = vp - r2;    v1 *= v1;
                    float v2 = o + d - r2; v2 *= v2;
                    s += fmaxf(v1, v2);
                }
            }
        }
        for (int off = 32; off; off >>= 1) s += __shfl_down(s, off, 64);
        if ((tid & 63) == 0) sh[tid >> 6] = s;
        __syncthreads();
        if (tid == 0) atomicAdd(&scal[5], sh[0] + sh[1] + sh[2] + sh[3]);
    }
    __threadfence();
    __syncthreads();
    if (tid == 0) {
        unsigned old = atomicAdd((unsigned int*)&scal[8], 1u);
        if (old == TAIL_BLOCKS - 1) {
            __threadfence();
            float pgs = atomicAdd(&scal[2], 0.f);
            float ents = atomicAdd(&scal[3], 0.f);
            float vfs = atomicAdd(&scal[5], 0.f);
            float pg = pgs / (float)BT;
            float vf = 0.5f * vfs / ((float)BT * (float)BT);
            float loss = pg - ents + vf;
            if (f32) {
                float* o = (float*)out;
                o[0] = loss; o[1] = pg; o[2] = ents; o[3] = vf;
            } else {
                u16* o = (u16*)out;
                o[0] = f2b(loss); o[1] = f2b(pg); o[2] = f2b(ents); o[3] = f2b(vf);
            }
        }
    }
}

extern "C" void kernel_launch(void* const* d_in, const int* in_sizes, int n_in,
                              void* d_out, int out_size, void* d_ws, size_t ws_size,
                              hipStream_t stream)
{
    const int* mask = (const int*)d_in[1];
    const int* a_tk = (const int*)d_in[3];

    float* p = (float*)d_ws;
    u16*   featbf = (u16*)p;            p += 524288;    // 1M u16
    float* zx     = p;                  p += 4194304;   // 16 MB
    u16*   hseqbf = (u16*)p;            p += 524288;    // 1M u16
    u16*   PF     = (u16*)p;            p += 131072;    // f16 Wr
    u16*   PBk    = (u16*)p;            p += 131072;    // bf16 Wk frag
    u16*   PBpim  = (u16*)p;            p += 524288;    // bf16 pimW frag
    u16*   PBpir  = (u16*)p;            p += 8192;      // bf16 [pirW|vW] frag
    float* scal   = p;                  p += 32;
    int*   flag   = (int*)p;            p += 4;
    float* partS  = p;                  p += 262144;
    float* partU  = p;                  p += 262144;
    float* za     = p;                  p += 4096;
    float* entpir = p;                  p += 4096;
    float* ppira  = p;                  p += 4096;
    float* vpred  = p;                  p += 4096;

    PrepPtrs P;
    P.x = d_in[0];
    P.W1 = d_in[7];  P.b1 = d_in[8];
    P.W2 = d_in[9];  P.b2 = d_in[10];
    P.W3 = d_in[11]; P.b3 = d_in[12];
    P.W4 = d_in[13]; P.b4 = d_in[14];
    P.Wk = d_in[15]; P.Wr = d_in[16];
    P.Wpir = d_in[18]; P.Wpim = d_in[20]; P.Wv = d_in[22];
    P.probe = (const u16*)d_in[15];
    P.featbf = featbf; P.PF = PF; P.PBk = PBk; P.PBpim = PBpim; P.PBpir = PBpir;
    P.scal = scal; P.flag = flag;

    prep_kernel<<<PACK_BLKS + CONV_BLKS, 256, 0, stream>>>(P);
    gemm_zx<<<dim3(16, 256), 256, 0, stream>>>(featbf, PBk, d_in[17], flag, zx);
    lstm_kernel<<<NB, 1024, 0, stream>>>(zx, PF, hseqbf);
    heads_kernel<<<64 + 64 * 256, 256, 0, stream>>>(
        hseqbf, PBpir, PBpim, d_in[19], d_in[23], d_in[21], flag, mask, a_tk,
        entpir, ppira, vpred, partS, partU, za);
    tail_kernel<<<TAIL_BLOCKS, 256, 0, stream>>>(
        partS, partU, za, entpir, ppira, vpred,
        d_in[2], d_in[4], d_in[5], d_in[6], scal, flag, (void*)d_out);
}

// Round 13
// 488.811 us; speedup vs baseline: 1.1798x; 1.0559x over previous
//
#include <hip/hip_runtime.h>

typedef unsigned short u16;
typedef unsigned int   u32;

#define BT   4096
#define TSEQ 64
#define NB   64

typedef __attribute__((ext_vector_type(8))) short  short8;
typedef __attribute__((ext_vector_type(4))) float  f32x4;
typedef __attribute__((ext_vector_type(2))) _Float16 h2;

__device__ __forceinline__ float bf(u16 v) {
    u32 u = ((u32)v) << 16;
    return __builtin_bit_cast(float, u);
}
__device__ __forceinline__ u16 f2b(float f) {
    u32 u = __builtin_bit_cast(u32, f);
    return (u16)((u + 0x7fffu + ((u >> 16) & 1u)) >> 16);  // RNE
}
__device__ __forceinline__ float lrelu(float x) { return x > 0.f ? x : 0.2f * x; }
__device__ __forceinline__ h2 i2h(int v) { return __builtin_bit_cast(h2, v); }
__device__ __forceinline__ float dot2(int hbits, int wbits, float acc) {
#if __has_builtin(__builtin_amdgcn_fdot2)
    return __builtin_amdgcn_fdot2(i2h(hbits), i2h(wbits), acc, false);
#else
    h2 a = i2h(hbits), b = i2h(wbits);
    return acc + (float)a.x * (float)b.x + (float)a.y * (float)b.y;
#endif
}
__device__ __forceinline__ float fsigm(float x) { return 1.f / (1.f + __expf(-x)); }
__device__ __forceinline__ float ftanh(float x) { return 1.f - 2.f / (__expf(2.f * x) + 1.f); }
__device__ __forceinline__ float ldf(const void* p, int i, int f32) {
    return f32 ? ((const float*)p)[i] : bf(((const u16*)p)[i]);
}
__device__ __forceinline__ u16 ldb(const void* p, int i, int f32) {
    return f32 ? f2b(((const float*)p)[i]) : ((const u16*)p)[i];
}

struct PrepPtrs {
    const void *x, *W1, *b1, *W2, *b2, *W3, *b3, *W4, *b4;
    const void *Wr, *Wk, *Wpim, *Wpir, *Wv;
    const u16* probe;
    u16 *featbf, *PF, *PBk, *PBpim, *PBpir;
    float* scal; int* flag;
};

// pack: each thread packs 8 consecutive k (one octet) for one column ->
// 8 coalesced reads + one contiguous 16B store (old: 2B scatter, ~16x WA)
#define PACK_BLKS 776   // PF 128 | PBk 128 | PBpim 512 | PBpir 8
#define CONV_BLKS 2048  // 2 images per block

// ================= K1: prep = sniff(inline) + pack + conv ===================
__global__ __launch_bounds__(256) void prep_kernel(PrepPtrs P)
{
    const int bid = blockIdx.x, tid = threadIdx.x;
    const int lane = tid & 63;
    u16 pv = P.probe[2 * lane];
    int e = (pv >> 7) & 0xFF;
    unsigned long long m = __ballot(pv == 0 || (e >= 100 && e <= 130));
    const int f32 = (__popcll(m) < 48) ? 1 : 0;

    if (bid == 0 && tid < 32) { P.scal[tid] = 0.f; if (tid == 0) *P.flag = f32; }

    if (bid < PACK_BLKS) {
        u16 t8[8];
        if (bid < 128) {                       // PF: Wr -> f16 chunks
            int gid = bid * 256 + tid;         // 32768: (oct, col)
            int col = gid & 1023, oct = gid >> 10;
#pragma unroll
            for (int j = 0; j < 8; j++) {
                float f = ldf(P.Wr, (oct * 8 + j) * 1024 + col, f32);
                _Float16 h = (_Float16)f;
                t8[j] = __builtin_bit_cast(unsigned short, h);
            }
            *(int4*)&P.PF[((size_t)oct * 1024 + col) * 8] = *(int4*)t8;
        } else if (bid < 256) {                // PBk: bf16 B-frag
            int gid = (bid - 128) * 256 + tid;
            int col = gid & 1023, oct = gid >> 10;
#pragma unroll
            for (int j = 0; j < 8; j++) t8[j] = ldb(P.Wk, (oct * 8 + j) * 1024 + col, f32);
            *(int4*)&P.PBk[((((size_t)(oct >> 2) << 10) + col) * 4 + (oct & 3)) * 8] = *(int4*)t8;
        } else if (bid < 768) {                // PBpim
            int gid = (bid - 256) * 256 + tid; // 131072: (oct, col)
            int col = gid & 4095, oct = gid >> 12;
#pragma unroll
            for (int j = 0; j < 8; j++) t8[j] = ldb(P.Wpim, (size_t)(oct * 8 + j) * 4096 + col, f32);
            *(int4*)&P.PBpim[((((size_t)(oct >> 2) << 12) + col) * 4 + (oct & 3)) * 8] = *(int4*)t8;
        } else {                               // PBpir: [pirW|vW|0]
            int gid = (bid - 768) * 256 + tid; // 2048: (oct, col)
            int col = gid & 63, oct = gid >> 6;
#pragma unroll
            for (int j = 0; j < 8; j++) {
                int k = oct * 8 + j;
                u16 v = 0;
                if (col < 36)       v = ldb(P.Wpir, k * 36 + col, f32);
                else if (col == 36) v = ldb(P.Wv, k, f32);
                t8[j] = v;
            }
            *(int4*)&P.PBpir[(((size_t)(oct >> 2) * 64 + col) * 4 + (oct & 3)) * 8] = *(int4*)t8;
        }
        return;
    }

    // ---- conv branch: 2 images per block; LDS-staged bf16 weights ----
    __shared__ __align__(16) u16 wl[19184];
    __shared__ float xs[2][832];
    __shared__ float c1[2][384];
    __shared__ float c2[2][480];
    __shared__ float c3[2][128];
    const int pair = bid - PACK_BLKS;
    const int sub = tid >> 7, stid = tid & 127;
    const int bt = pair * 2 + sub;

    {
        const void* sp[8] = {P.W1, P.b1, P.W2, P.b2, P.W3, P.b3, P.W4, P.b4};
        const int   sn[8] = {512, 16, 2048, 32, 8192, 64, 8192, 128};
        int o = 0;
        for (int s = 0; s < 8; s++) {
            for (int i = tid; i < sn[s]; i += 256) wl[o + i] = ldb(sp[s], i, f32);
            o += sn[s];
        }
    }
    for (int i = stid; i < 832; i += 128) xs[sub][i] = ldf(P.x, bt * 832 + i, f32);
    __syncthreads();

    for (int idx = stid; idx < 96; idx += 128) {
        int pos = idx >> 2, g = idx & 3;
        int oh = pos >> 2, ow = pos & 3;
        float a0 = bf(wl[512 + g * 4]), a1 = bf(wl[513 + g * 4]),
              a2 = bf(wl[514 + g * 4]), a3 = bf(wl[515 + g * 4]);
        for (int kh = 0; kh < 2; kh++)
            for (int kw = 0; kw < 2; kw++)
#pragma unroll
                for (int ic = 0; ic < 8; ic++) {
                    float xv = xs[sub][(2 * oh + kh) * 64 + (2 * ow + kw) * 8 + ic];
                    ushort4 w = *(const ushort4*)&wl[((kh * 2 + kw) * 8 + ic) * 16 + g * 4];
                    a0 += xv * bf(w.x); a1 += xv * bf(w.y);
                    a2 += xv * bf(w.z); a3 += xv * bf(w.w);
                }
        c1[sub][pos * 16 + g * 4]     = lrelu(a0);
        c1[sub][pos * 16 + g * 4 + 1] = lrelu(a1);
        c1[sub][pos * 16 + g * 4 + 2] = lrelu(a2);
        c1[sub][pos * 16 + g * 4 + 3] = lrelu(a3);
    }
    __syncthreads();

    for (int idx = stid; idx < 120; idx += 128) {
        int pos = idx >> 3, g = idx & 7;
        int oh = pos / 3, ow = pos % 3;
        float a0 = bf(wl[2576 + g * 4]), a1 = bf(wl[2577 + g * 4]),
              a2 = bf(wl[2578 + g * 4]), a3 = bf(wl[2579 + g * 4]);
        for (int kh = 0; kh < 2; kh++)
            for (int kw = 0; kw < 2; kw++)
#pragma unroll
                for (int ic = 0; ic < 16; ic++) {
                    float xv = c1[sub][((oh + kh) * 4 + (ow + kw)) * 16 + ic];
                    ushort4 w = *(const ushort4*)&wl[528 + ((kh * 2 + kw) * 16 + ic) * 32 + g * 4];
                    a0 += xv * bf(w.x); a1 += xv * bf(w.y);
                    a2 += xv * bf(w.z); a3 += xv * bf(w.w);
                }
        c2[sub][pos * 32 + g * 4]     = lrelu(a0);
        c2[sub][pos * 32 + g * 4 + 1] = lrelu(a1);
        c2[sub][pos * 32 + g * 4 + 2] = lrelu(a2);
        c2[sub][pos * 32 + g * 4 + 3] = lrelu(a3);
    }
    __syncthreads();

    for (int idx = stid; idx < 32; idx += 128) {
        int oh = idx >> 4, g = idx & 15;
        float a0 = bf(wl[10800 + g * 4]), a1 = bf(wl[10801 + g * 4]),
              a2 = bf(wl[10802 + g * 4]), a3 = bf(wl[10803 + g * 4]);
        for (int kh = 0; kh < 2; kh++)
            for (int kw = 0; kw < 2; kw++)
#pragma unroll
                for (int ic = 0; ic < 32; ic++) {
                    float xv = c2[sub][((2 * oh + kh) * 3 + kw) * 32 + ic];
                    ushort4 w = *(const ushort4*)&wl[2608 + ((kh * 2 + kw) * 32 + ic) * 64 + g * 4];
                    a0 += xv * bf(w.x); a1 += xv * bf(w.y);
                    a2 += xv * bf(w.z); a3 += xv * bf(w.w);
                }
        c3[sub][oh * 64 + g * 4]     = lrelu(a0);
        c3[sub][oh * 64 + g * 4 + 1] = lrelu(a1);
        c3[sub][oh * 64 + g * 4 + 2] = lrelu(a2);
        c3[sub][oh * 64 + g * 4 + 3] = lrelu(a3);
    }
    __syncthreads();

    for (int idx = stid; idx < 64; idx += 128) {
        int oh = idx >> 5, g = idx & 31;
        float a0 = bf(wl[19056 + g * 4]), a1 = bf(wl[19057 + g * 4]),
              a2 = bf(wl[19058 + g * 4]), a3 = bf(wl[19059 + g * 4]);
#pragma unroll
        for (int ic = 0; ic < 64; ic++) {
            float xv = c3[sub][oh * 64 + ic];
            ushort4 w = *(const ushort4*)&wl[10864 + ic * 128 + g * 4];
            a0 += xv * bf(w.x); a1 += xv * bf(w.y);
            a2 += xv * bf(w.z); a3 += xv * bf(w.w);
        }
        P.featbf[bt * 256 + (g * 4 + 0) * 2 + oh] = f2b(lrelu(a0));
        P.featbf[bt * 256 + (g * 4 + 1) * 2 + oh] = f2b(lrelu(a1));
        P.featbf[bt * 256 + (g * 4 + 2) * 2 + oh] = f2b(lrelu(a2));
        P.featbf[bt * 256 + (g * 4 + 3) * 2 + oh] = f2b(lrelu(a3));
    }
}

// ================= K2: zx = featbf @ Wk + b (MFMA) ==========================
__global__ __launch_bounds__(256) void gemm_zx(
    const u16* __restrict__ Abf, const u16* __restrict__ PB,
    const void* __restrict__ bias, const int* __restrict__ flag,
    float* __restrict__ out)
{
    __shared__ __align__(16) u16 As[16 * 264];
    const int mb = blockIdx.y, nb = blockIdx.x, tid = threadIdx.x;
    const int f32 = *flag;
    const int m0 = mb * 16;
    {
        int row = tid >> 4, part = tid & 15;
        const f32x4* src = (const f32x4*)&Abf[(size_t)(m0 + row) * 256 + part * 16];
        f32x4 v0 = src[0], v1 = src[1];
        *(f32x4*)&As[row * 264 + part * 16] = v0;
        *(f32x4*)&As[row * 264 + part * 16 + 8] = v1;
    }
    __syncthreads();
    const int wv = tid >> 6, lane = tid & 63;
    const int colw = lane & 15, q = lane >> 4;
    const int n = nb * 64 + wv * 16 + colw;
    f32x4 acc = {0.f, 0.f, 0.f, 0.f};
#pragma unroll
    for (int kt = 0; kt < 8; kt++) {
        short8 a = *(const short8*)&As[colw * 264 + kt * 32 + q * 8];
        short8 b = *(const short8*)&PB[((((size_t)kt << 10) + n) * 4 + q) * 8];
        acc = __builtin_amdgcn_mfma_f32_16x16x32_bf16(a, b, acc, 0, 0, 0);
    }
    const float bj = ldf(bias, n, f32);
#pragma unroll
    for (int r = 0; r < 4; r++) {
        int row = q * 4 + r;
        out[(size_t)(m0 + row) * 1024 + n] = acc[r] + bj;
    }
}

// ================= K3: LSTM (R10 structure — at L1 stream floor) ============
#define NPRE 18
#define NLDS 7
#define NSTR (32 - NPRE - NLDS)
__global__ __launch_bounds__(1024)
__attribute__((amdgpu_waves_per_eu(4, 4)))
void lstm_kernel(
    const float* __restrict__ zx, const u16* __restrict__ PF,
    u16* __restrict__ hseqbf)
{
    __shared__ float zp[1024];
    __shared__ __align__(16) u16 h16[256];
    __shared__ u16 hist[TSEQ * 256];                 // 32 KB
    __shared__ __align__(16) int4 wlds[NLDS * 1024]; // 112 KB
    const int b = blockIdx.x, tid = threadIdx.x;
    float c = 0.f;
    const int4* Pw = (const int4*)PF;

    int4 wr[NPRE];
#pragma unroll
    for (int j = 0; j < NPRE; j++) wr[j] = Pw[j * 1024 + tid];
#pragma unroll
    for (int j = 0; j < NLDS; j++) wlds[j * 1024 + tid] = Pw[(NPRE + j) * 1024 + tid];
    if (tid < 256) h16[tid] = 0;
    __syncthreads();

    for (int t = 0; t < TSEQ; t++) {
        int4 ws[NSTR];
#pragma unroll
        for (int j = 0; j < NSTR; j++) ws[j] = Pw[(NPRE + NLDS + j) * 1024 + tid];
        float zxv = zx[(size_t)(b * TSEQ + t) * 1024 + tid];

        float a0 = 0.f, a1 = 0.f, a2 = 0.f, a3 = 0.f;
#pragma unroll
        for (int j = 0; j < NPRE; j++) {
            int4 hv = *(const int4*)&h16[j * 8];
            a0 = dot2(hv.x, wr[j].x, a0);
            a1 = dot2(hv.y, wr[j].y, a1);
            a2 = dot2(hv.z, wr[j].z, a2);
            a3 = dot2(hv.w, wr[j].w, a3);
        }
#pragma unroll
        for (int j = 0; j < NLDS; j++) {
            int4 hv = *(const int4*)&h16[(NPRE + j) * 8];
            int4 w = wlds[j * 1024 + tid];
            a0 = dot2(hv.x, w.x, a0);
            a1 = dot2(hv.y, w.y, a1);
            a2 = dot2(hv.z, w.z, a2);
            a3 = dot2(hv.w, w.w, a3);
        }
#pragma unroll
        for (int j = 0; j < NSTR; j++) {
            int4 hv = *(const int4*)&h16[(NPRE + NLDS + j) * 8];
            a0 = dot2(hv.x, ws[j].x, a0);
            a1 = dot2(hv.y, ws[j].y, a1);
            a2 = dot2(hv.z, ws[j].z, a2);
            a3 = dot2(hv.w, ws[j].w, a3);
        }
        zp[tid] = ((a0 + a1) + (a2 + a3)) + zxv;
        __syncthreads();
        if (tid < 256) {
            float ai = zp[tid], af = zp[256 + tid], ag = zp[512 + tid], ao = zp[768 + tid];
            float ig = fsigm(ai), fg = fsigm(af), og = fsigm(ao);
            float gg = ftanh(ag);
            c = fg * c + ig * gg;
            float h = og * ftanh(c);
            h16[tid] = __builtin_bit_cast(unsigned short, (_Float16)h);
            hist[t * 256 + tid] = f2b(h);
        }
        __syncthreads();
    }
    for (int i = tid; i < TSEQ * 256; i += 1024)
        hseqbf[(size_t)b * (TSEQ * 256) + i] = hist[i];
}

// ================= K4: pir head + vpred (64 blocks) =========================
__global__ __launch_bounds__(256) void pir_kernel(
    const u16* __restrict__ Abf, const u16* __restrict__ PB,
    const void* __restrict__ pir_b, const void* __restrict__ v_b,
    const int* __restrict__ flag, const int* __restrict__ a_taken,
    float* __restrict__ entpir, float* __restrict__ ppira, float* __restrict__ vpred)
{
    __shared__ __align__(16) u16 As[64 * 264];
    const int tid = threadIdx.x;
    const int wv = tid >> 6, lane = tid & 63;
    const int colw = lane & 15, q = lane >> 4;
    const int f32 = *flag;
    const int m0 = blockIdx.x * 64;

    for (int idx = tid; idx < 1024; idx += 256) {
        int row = idx >> 4, part = idx & 15;
        const f32x4* src = (const f32x4*)&Abf[(size_t)(m0 + row) * 256 + part * 16];
        f32x4 v0 = src[0], v1 = src[1];
        *(f32x4*)&As[row * 264 + part * 16] = v0;
        *(f32x4*)&As[row * 264 + part * 16 + 8] = v1;
    }
    __syncthreads();
    f32x4 acc[4];
#pragma unroll
    for (int nt = 0; nt < 4; nt++) acc[nt] = (f32x4){0.f, 0.f, 0.f, 0.f};
#pragma unroll
    for (int kt = 0; kt < 8; kt++) {
        short8 a = *(const short8*)&As[(wv * 16 + colw) * 264 + kt * 32 + q * 8];
#pragma unroll
        for (int nt = 0; nt < 4; nt++) {
            short8 b = *(const short8*)&PB[((((size_t)kt * 64) + nt * 16 + colw) * 4 + q) * 8];
            acc[nt] = __builtin_amdgcn_mfma_f32_16x16x32_bf16(a, b, acc[nt], 0, 0, 0);
        }
    }
    float* zq = (float*)&As[wv * 4224];   // wave-local 16x65 overlay
#pragma unroll
    for (int nt = 0; nt < 4; nt++) {
        int col = nt * 16 + colw;
        float bj = (col < 36) ? ldf(pir_b, col, f32)
                              : (col == 36 ? ldf(v_b, 0, f32) : 0.f);
#pragma unroll
        for (int r = 0; r < 4; r++)
            zq[(q * 4 + r) * 65 + col] = acc[nt][r] + bj;
    }
    if (lane < 16) {
        int R = m0 + wv * 16 + lane;
        const float* zrow = &zq[lane * 65];
        float Z = 0.f, U = 0.f;
        for (int cc = 0; cc < 36; cc++) {
            float z = zrow[cc];
            float ev = __expf(z);
            Z += ev; U += ev * z;
        }
        entpir[R] = logf(Z) - U / Z;
        ppira[R]  = __expf(zrow[a_taken[R]]) / Z;
        vpred[R]  = zrow[36];
    }
}

// ================= K5: pim — M=32 tiles, fused masked-softmax partials ======
__global__ __launch_bounds__(256) void pim_kernel(
    const u16* __restrict__ Abf, const u16* __restrict__ PB,
    const void* __restrict__ pim_b, const int* __restrict__ flag,
    const int* __restrict__ mask, const int* __restrict__ a_taken,
    float* __restrict__ partS, float* __restrict__ partU, float* __restrict__ za)
{
    __shared__ __align__(16) u16 As[32 * 264];   // 16.9 KB
    __shared__ float redS[4][32], redU[4][32];
    const int nb = blockIdx.x, mb = blockIdx.y, tid = threadIdx.x;
    const int wv = tid >> 6, lane = tid & 63;
    const int colw = lane & 15, q = lane >> 4;
    const int f32 = *flag;
    const int m0 = mb * 32;

    for (int idx = tid; idx < 512; idx += 256) {
        int row = idx >> 4, part = idx & 15;
        const f32x4* src = (const f32x4*)&Abf[(size_t)(m0 + row) * 256 + part * 16];
        f32x4 v0 = src[0], v1 = src[1];
        *(f32x4*)&As[row * 264 + part * 16] = v0;
        *(f32x4*)&As[row * 264 + part * 16 + 8] = v1;
    }
    __syncthreads();
    const int n = nb * 64 + wv * 16 + colw;
    f32x4 acc0 = {0.f, 0.f, 0.f, 0.f}, acc1 = {0.f, 0.f, 0.f, 0.f};
#pragma unroll
    for (int kt = 0; kt < 8; kt++) {
        short8 b = *(const short8*)&PB[((((size_t)kt << 12) + n) * 4 + q) * 8];
        short8 a0 = *(const short8*)&As[colw * 264 + kt * 32 + q * 8];
        short8 a1 = *(const short8*)&As[(16 + colw) * 264 + kt * 32 + q * 8];
        acc0 = __builtin_amdgcn_mfma_f32_16x16x32_bf16(a0, b, acc0, 0, 0, 0);
        acc1 = __builtin_amdgcn_mfma_f32_16x16x32_bf16(a1, b, acc1, 0, 0, 0);
    }
    const float bj = ldf(pim_b, n, f32);
#pragma unroll
    for (int half = 0; half < 2; half++) {
        const f32x4& acc = half ? acc1 : acc0;
        float sv[4], uv[4];
#pragma unroll
        for (int r = 0; r < 4; r++) {
            int row = m0 + half * 16 + q * 4 + r;
            float z = acc[r] + bj;
            int mm = mask[(size_t)row * 4096 + n];
            float ev = __expf(z);
            sv[r] = mm ? ev : 0.f;
            uv[r] = mm ? ev * z : 0.f;
            if (n == a_taken[row]) za[row] = z;
        }
#pragma unroll
        for (int r = 0; r < 4; r++) {
            for (int off = 1; off < 16; off <<= 1) {
                sv[r] += __shfl_xor(sv[r], off, 16);
                uv[r] += __shfl_xor(uv[r], off, 16);
            }
            if (colw == 0) {
                redS[wv][half * 16 + q * 4 + r] = sv[r];
                redU[wv][half * 16 + q * 4 + r] = uv[r];
            }
        }
    }
    __syncthreads();
    if (tid < 32) {
        float S = redS[0][tid] + redS[1][tid] + redS[2][tid] + redS[3][tid];
        float U = redU[0][tid] + redU[1][tid] + redU[2][tid] + redU[3][tid];
        partS[(size_t)(m0 + tid) * 64 + nb] = S;
        partU[(size_t)(m0 + tid) * 64 + nb] = U;
    }
}

// ================= K6: tail = pimfin + gae + pg + vf + fin (ticket) =========
#define TAIL_BLOCKS (16 + 256)
__global__ __launch_bounds__(256) void tail_kernel(
    const float* __restrict__ partS, const float* __restrict__ partU,
    const float* __restrict__ za,
    const float* __restrict__ entpir, const float* __restrict__ ppira,
    const float* __restrict__ vpred,
    const void* __restrict__ lgold, const void* __restrict__ gae,
    const void* __restrict__ ovp, const void* __restrict__ ret,
    float* __restrict__ scal, const int* __restrict__ flag,
    void* __restrict__ out)
{
    const int bid = blockIdx.x, tid = threadIdx.x;
    const int f32 = *flag;
    __shared__ float sh[8];
    __shared__ float mst[2];
    if (bid < 16) {
        const int r = bid * 256 + tid;
        float S = 0.f, U = 0.f;
#pragma unroll
        for (int t2 = 0; t2 < 64; t2++) {
            S += partS[(size_t)r * 64 + t2];
            U += partU[(size_t)r * 64 + t2];
        }
        float entpim = logf(S) - U / S;
        float ppima = __expf(za[r]) / S;
        float s = 0.f, s2 = 0.f;
        if (f32) {
            const float* gp = (const float*)gae;
            for (int i = tid; i < BT; i += 256) { float v = gp[i]; s += v; s2 += v * v; }
        } else {
            const u16* gp = (const u16*)gae;
            for (int i = tid; i < BT; i += 256) { float v = bf(gp[i]); s += v; s2 += v * v; }
        }
        for (int off = 32; off; off >>= 1) {
            s += __shfl_down(s, off, 64); s2 += __shfl_down(s2, off, 64);
        }
        if ((tid & 63) == 0) { sh[tid >> 6] = s; sh[4 + (tid >> 6)] = s2; }
        __syncthreads();
        if (tid == 0) {
            float Sa = sh[0] + sh[1] + sh[2] + sh[3];
            float S2a = sh[4] + sh[5] + sh[6] + sh[7];
            float mean = Sa / (float)BT;
            float var = S2a / (float)BT - mean * mean;
            mst[0] = mean; mst[1] = sqrtf(fmaxf(var, 0.f));
        }
        __syncthreads();
        float mean = mst[0], sd = mst[1];
        float p = (r & 1) ? ppima : ppira[r];
        float ln = logf(p);
        float rt = __expf(ln - ldf(lgold, r, f32));
        float g = (ldf(gae, r, f32) - mean) / (sd + 1e-8f);
        float rtc = fminf(fmaxf(rt, 0.8f), 1.2f);
        float pg = fmaxf(-g * rt, -g * rtc);
        float e12 = entpir[r] + entpim;
        for (int off = 32; off; off >>= 1) {
            pg += __shfl_down(pg, off, 64);
            e12 += __shfl_down(e12, off, 64);
        }
        if ((tid & 63) == 0) {
            atomicAdd(&scal[2], pg);
            atomicAdd(&scal[3], e12);
        }
    } else {
        const int i0 = (bid - 16) * 16;
        float s = 0.f;
        if (f32) {
            const float* rp = (const float*)ret;
            const float* op = (const float*)ovp;
            for (int rr = 0; rr < 16; rr++) {
                float vp = vpred[i0 + rr];
                for (int j = tid; j < BT; j += 256) {
                    float r2 = rp[j], o = op[j];
                    float d = fminf(fmaxf(vp - o, -0.2f), 0.2f);
                    float v1 = vp - r2;    v1 *= v1;
                    float v2 = o + d - r2; v2 *= v2;
                    s += fmaxf(v1, v2);
                }
            }
        } else {
            const u16* rp = (const u16*)ret;
            const u16* op = (const u16*)ovp;
            for (int rr = 0; rr < 16; rr++) {
                float vp = vpred[i0 + rr];
                for (int j = tid; j < BT; j += 256) {
                    float r2 = bf(rp[j]), o = bf(op[j]);
                    float d = fminf(fmaxf(vp - o, -0.2f), 0.2f);
                    float v1 = vp - r2;    v1 *= v1;
                    float v2 = o + d - r2; v2 *= v2;
                    s += fmaxf(v1, v2);
                }
            }
        }
        for (int off = 32; off; off >>= 1) s += __shfl_down(s, off, 64);
        if ((tid & 63) == 0) sh[tid >> 6] = s;
        __syncthreads();
        if (tid == 0) atomicAdd(&scal[5], sh[0] + sh[1] + sh[2] + sh[3]);
    }
    __threadfence();
    __syncthreads();
    if (tid == 0) {
        unsigned old = atomicAdd((unsigned int*)&scal[8], 1u);
        if (old == TAIL_BLOCKS - 1) {
            __threadfence();
            float pgs = atomicAdd(&scal[2], 0.f);
            float ents = atomicAdd(&scal[3], 0.f);
            float vfs = atomicAdd(&scal[5], 0.f);
            float pg = pgs / (float)BT;
            float vf = 0.5f * vfs / ((float)BT * (float)BT);
            float loss = pg - ents + vf;
            if (f32) {
                float* o = (float*)out;
                o[0] = loss; o[1] = pg; o[2] = ents; o[3] = vf;
            } else {
                u16* o = (u16*)out;
                o[0] = f2b(loss); o[1] = f2b(pg); o[2] = f2b(ents); o[3] = f2b(vf);
            }
        }
    }
}

extern "C" void kernel_launch(void* const* d_in, const int* in_sizes, int n_in,
                              void* d_out, int out_size, void* d_ws, size_t ws_size,
                              hipStream_t stream)
{
    const int* mask = (const int*)d_in[1];
    const int* a_tk = (const int*)d_in[3];

    float* p = (float*)d_ws;
    u16*   featbf = (u16*)p;            p += 524288;    // 1M u16
    float* zx     = p;                  p += 4194304;   // 16 MB
    u16*   hseqbf = (u16*)p;            p += 524288;    // 1M u16
    u16*   PF     = (u16*)p;            p += 131072;    // f16 Wr
    u16*   PBk    = (u16*)p;            p += 131072;    // bf16 Wk frag
    u16*   PBpim  = (u16*)p;            p += 524288;    // bf16 pimW frag
    u16*   PBpir  = (u16*)p;            p += 8192;      // bf16 [pirW|vW] frag
    float* scal   = p;                  p += 32;
    int*   flag   = (int*)p;            p += 4;
    float* partS  = p;                  p += 262144;
    float* partU  = p;                  p += 262144;
    float* za     = p;                  p += 4096;
    float* entpir = p;                  p += 4096;
    float* ppira  = p;                  p += 4096;
    float* vpred  = p;                  p += 4096;

    PrepPtrs P;
    P.x = d_in[0];
    P.W1 = d_in[7];  P.b1 = d_in[8];
    P.W2 = d_in[9];  P.b2 = d_in[10];
    P.W3 = d_in[11]; P.b3 = d_in[12];
    P.W4 = d_in[13]; P.b4 = d_in[14];
    P.Wk = d_in[15]; P.Wr = d_in[16];
    P.Wpir = d_in[18]; P.Wpim = d_in[20]; P.Wv = d_in[22];
    P.probe = (const u16*)d_in[15];
    P.featbf = featbf; P.PF = PF; P.PBk = PBk; P.PBpim = PBpim; P.PBpir = PBpir;
    P.scal = scal; P.flag = flag;

    prep_kernel<<<PACK_BLKS + CONV_BLKS, 256, 0, stream>>>(P);
    gemm_zx<<<dim3(16, 256), 256, 0, stream>>>(featbf, PBk, d_in[17], flag, zx);
    lstm_kernel<<<NB, 1024, 0, stream>>>(zx, PF, hseqbf);
    pir_kernel<<<64, 256, 0, stream>>>(hseqbf, PBpir, d_in[19], d_in[23], flag,
                                       a_tk, entpir, ppira, vpred);
    pim_kernel<<<dim3(64, 128), 256, 0, stream>>>(hseqbf, PBpim, d_in[21], flag,
                                                  mask, a_tk, partS, partU, za);
    tail_kernel<<<TAIL_BLOCKS, 256, 0, stream>>>(
        partS, partU, za, entpir, ppira, vpred,
        d_in[2], d_in[4], d_in[5], d_in[6], scal, flag, (void*)d_out);
}